// Round 8
// baseline (133.738 us; speedup 1.0000x reference)
//
#include <hip/hip_runtime.h>
#include <math.h>

#define D_IN 512
#define D_HID 128
#define D_OUT 512
#define N_ENT 262144

#define K3_BLOCKS 2048
#define WAVES_PER_BLOCK 4
#define TOTAL_WAVES (K3_BLOCKS * WAVES_PER_BLOCK)   // 8192
#define ROWS_PER_WAVE (N_ENT / TOTAL_WAVES)         // 32

// ws float-offsets
#define KV_OFF    0                // 512: kvec pre-scaled by 1/sqrt(H)
#define BS_OFF    512              // 2048 block sums of exp(logit)
#define BT5_OFF_F 2560             // byte 10240 (8B aligned): 2048*5 u64 keys

#define INV_SQRT_H 0.08838834764831845f  // 1/sqrt(128)

typedef float f32x4 __attribute__((ext_vector_type(4)));
typedef unsigned long long u64;

#define NTLD(p) __builtin_nontemporal_load(p)

__device__ inline u64 pack_key(float v, int idx) {
    unsigned u = __float_as_uint(v);
    u = (u & 0x80000000u) ? ~u : (u | 0x80000000u);   // order-preserving
    return ((u64)u << 32) | (unsigned)(~idx);          // ties -> smaller idx wins
}
__device__ inline float unpack_val(u64 k) {
    unsigned o = (unsigned)(k >> 32);
    unsigned u = (o & 0x80000000u) ? (o & 0x7FFFFFFFu) : ~o;
    return __uint_as_float(u);
}
__device__ inline int unpack_idx(u64 k) { return (int)~(unsigned)(k & 0xFFFFFFFFu); }

#define INS5(kk) do { u64 _k = (kk); if (_k > t4) {            \
    if (_k > t0)      { t4=t3;t3=t2;t2=t1;t1=t0;t0=_k; }       \
    else if (_k > t1) { t4=t3;t3=t2;t2=t1;t1=_k; }             \
    else if (_k > t2) { t4=t3;t3=t2;t2=_k; }                   \
    else if (_k > t3) { t4=t3;t3=_k; }                         \
    else              { t4=_k; } } } while (0)

// ---------- K1: fused front — q = Wq@c+bq (redundant/block), kvec slice ----------
__global__ __launch_bounds__(512) void k_front(const float* __restrict__ c,
        const float* __restrict__ Wq, const float* __restrict__ bq,
        const float* __restrict__ Wk, float* __restrict__ ws) {
    __shared__ float qpart[512];
    __shared__ float qs[D_HID];
    __shared__ float kpart[8][64];
    const int t = threadIdx.x;
    {   // phase 1: q, 4 threads per row (quarter-row each)
        const int row = t >> 2, qtr = t & 3;
        const f32x4* wq = (const f32x4*)(Wq + (size_t)row * D_IN + qtr * 128);
        const f32x4* cv = (const f32x4*)(c + qtr * 128);
        float acc = 0.f;
        #pragma unroll 16
        for (int j = 0; j < 32; ++j) {
            f32x4 a = wq[j], b = cv[j];
            acc += a.x*b.x + a.y*b.y + a.z*b.z + a.w*b.w;
        }
        qpart[t] = acc;
    }
    __syncthreads();
    if (t < D_HID) qs[t] = (qpart[4*t] + qpart[4*t+1]) + (qpart[4*t+2] + qpart[4*t+3]) + bq[t];
    __syncthreads();
    {   // phase 2: kvec[d0..d0+64), wave g covers h in [16g,16g+16)
        const int g = t >> 6, d = t & 63;
        const int d0 = blockIdx.x * 64;
        const float* col = Wk + (size_t)(g * 16) * D_IN + d0 + d;
        float acc = 0.f;
        #pragma unroll 16
        for (int h = 0; h < 16; ++h) acc += col[(size_t)h * D_IN] * qs[g*16 + h];
        kpart[g][d] = acc;
    }
    __syncthreads();
    if (t < 64) {
        float kv = ((kpart[0][t] + kpart[1][t]) + (kpart[2][t] + kpart[3][t]))
                 + ((kpart[4][t] + kpart[5][t]) + (kpart[6][t] + kpart[7][t]));
        ws[KV_OFF + blockIdx.x*64 + t] = kv * INV_SQRT_H;   // pre-scale
    }
}

// ---------- K2: logits + softmax-sum + per-block top5 ----------
// Software-pipelined: rows it+2/it+3 prefetched during compute of it/it+1.
// No online max: logits ~ N(0,1) (max ~5, exp<150) -> direct sum of exp is
// safe in fp32 to logit ~80. Removes the loop-carried fmax/rescale chain.
__global__ __launch_bounds__(256) void k_logits(const float* __restrict__ E,
                                                float* __restrict__ ws) {
    const int t = threadIdx.x;
    const int l = t & 63;
    const int w = t >> 6;
    const int wg = blockIdx.x * WAVES_PER_BLOCK + w;
    const long row0 = (long)wg * ROWS_PER_WAVE;

    const f32x4* kv = (const f32x4*)(ws + KV_OFF);
    const f32x4 k0 = kv[l], k1 = kv[64 + l];

    float s = 0.f;
    u64 t0 = 0, t1 = 0, t2 = 0, t3 = 0, t4 = 0;   // 0 < any real key

    const float* rbase = E + row0 * (long)D_IN;
    f32x4 a0 = NTLD((const f32x4*)rbase + l);
    f32x4 a1 = NTLD((const f32x4*)rbase + 64 + l);
    f32x4 b0 = NTLD((const f32x4*)(rbase + D_IN) + l);
    f32x4 b1 = NTLD((const f32x4*)(rbase + D_IN) + 64 + l);

#define BODY(IT)                                                              \
    {                                                                         \
        float d0 = a0.x*k0.x + a0.y*k0.y + a0.z*k0.z + a0.w*k0.w              \
                 + a1.x*k1.x + a1.y*k1.y + a1.z*k1.z + a1.w*k1.w;             \
        float d1 = b0.x*k0.x + b0.y*k0.y + b0.z*k0.z + b0.w*k0.w              \
                 + b1.x*k1.x + b1.y*k1.y + b1.z*k1.z + b1.w*k1.w;             \
        _Pragma("unroll")                                                     \
        for (int mm = 32; mm > 0; mm >>= 1) {                                 \
            d0 += __shfl_xor(d0, mm, 64);                                     \
            d1 += __shfl_xor(d1, mm, 64);                                     \
        }                                                                     \
        s += __expf(d0) + __expf(d1);                                         \
        INS5(pack_key(d0, (int)row0 + (IT)));                                 \
        INS5(pack_key(d1, (int)row0 + (IT) + 1));                             \
    }

    for (int it = 0; it < ROWS_PER_WAVE - 2; it += 2) {
        const float* nb = rbase + (size_t)(it + 2) * D_IN;
        f32x4 c0 = NTLD((const f32x4*)nb + l);
        f32x4 c1 = NTLD((const f32x4*)nb + 64 + l);
        f32x4 e0 = NTLD((const f32x4*)(nb + D_IN) + l);
        f32x4 e1 = NTLD((const f32x4*)(nb + D_IN) + 64 + l);
        BODY(it);
        a0 = c0; a1 = c1; b0 = e0; b1 = e1;
    }
    BODY(ROWS_PER_WAVE - 2);
#undef BODY

    __shared__ float ss[WAVES_PER_BLOCK];
    __shared__ u64 skey[WAVES_PER_BLOCK][5];
    if (l == 0) {
        ss[w] = s;
        skey[w][0]=t0; skey[w][1]=t1; skey[w][2]=t2; skey[w][3]=t3; skey[w][4]=t4;
    }
    __syncthreads();
    if (t == 0) {
        float S = (ss[0] + ss[1]) + (ss[2] + ss[3]);
        u64 t0=0,t1=0,t2=0,t3=0,t4=0;
        #pragma unroll
        for (int j = 0; j < WAVES_PER_BLOCK*5; ++j) INS5(skey[j/5][j%5]);
        const int b = blockIdx.x;
        ws[BS_OFF + b] = S;
        u64* bt = (u64*)ws + (BT5_OFF_F/2) + (size_t)b * 5;
        bt[0]=t0; bt[1]=t1; bt[2]=t2; bt[3]=t3; bt[4]=t4;
    }
}

// ---------- K3: redundant merge + u -> h -> out  (64 blocks x 512) ----------
__global__ __launch_bounds__(512) void k_vo(const float* __restrict__ E,
        const float* __restrict__ Wv, const float* __restrict__ bv,
        const float* __restrict__ Wo, const float* __restrict__ bo,
        const float* __restrict__ ws, float* __restrict__ out) {
    __shared__ u64   mwc[8][5];
    __shared__ float selv_sh[5];
    __shared__ int   seli_sh[5];
    __shared__ float wn_sh[5];
    __shared__ float zp[8];
    __shared__ float Wsum_sh;
    __shared__ float u_sh[D_IN];
    __shared__ float hp[512];
    __shared__ float h_sh[D_HID];
    const int t = threadIdx.x;
    const int l = t & 63;
    const int w = t >> 6;
    const u64* cand = (const u64*)ws + (BT5_OFF_F/2);

    // per-thread top5 over 20 candidates each (10240 total)
    u64 t0=0,t1=0,t2=0,t3=0,t4=0;
    #pragma unroll 4
    for (int j = 0; j < 20; ++j) INS5(cand[t + 512*j]);

    // wave top5: 5 rounds of extract-max
    {
        int pos = 0;
        u64 g0=0,g1=0,g2=0,g3=0,g4=0;
        #pragma unroll
        for (int r = 0; r < 5; ++r) {
            u64 head = pos==0?t0 : pos==1?t1 : pos==2?t2 : pos==3?t3 : pos==4?t4 : 0ULL;
            u64 wm = head;
            #pragma unroll
            for (int mm = 1; mm < 64; mm <<= 1) {
                u64 o = __shfl_xor(wm, mm, 64);
                wm = (o > wm) ? o : wm;
            }
            if (head == wm && wm != 0ULL) pos++;
            if (r==0) g0=wm; else if (r==1) g1=wm; else if (r==2) g2=wm;
            else if (r==3) g3=wm; else g4=wm;
        }
        if (l == 0) { mwc[w][0]=g0; mwc[w][1]=g1; mwc[w][2]=g2; mwc[w][3]=g3; mwc[w][4]=g4; }
    }
    __syncthreads();

    // cross-wave merge on wave 0 (lanes 0..7 present list heads)
    if (w == 0) {
        int pos = 0;
        #pragma unroll
        for (int r = 0; r < 5; ++r) {
            u64 head = (l < 8 && pos < 5) ? mwc[l][pos] : 0ULL;
            u64 wm = head;
            #pragma unroll
            for (int mm = 1; mm < 64; mm <<= 1) {
                u64 o = __shfl_xor(wm, mm, 64);
                wm = (o > wm) ? o : wm;
            }
            if (head == wm && wm != 0ULL) pos++;
            if (l == 0) { selv_sh[r] = unpack_val(wm); seli_sh[r] = unpack_idx(wm); }
        }
    }
    __syncthreads();

    // Z = sum_b S_b (no rescale needed; see k_logits comment)
    {
        float z = 0.f;
        #pragma unroll
        for (int k = 0; k < K3_BLOCKS/512; ++k) z += ws[BS_OFF + t + 512*k];
        #pragma unroll
        for (int mm = 1; mm < 64; mm <<= 1) z += __shfl_xor(z, mm, 64);
        if (l == 0) zp[w] = z;
    }
    __syncthreads();
    if (t == 0) {
        float Z = ((zp[0]+zp[1]) + (zp[2]+zp[3])) + ((zp[4]+zp[5]) + (zp[6]+zp[7]));
        float wsum = 0.f;
        #pragma unroll
        for (int r = 0; r < 5; ++r) {
            float wv = __expf(selv_sh[r]) / Z;
            wn_sh[r] = wv;
            wsum += wv;
        }
        Wsum_sh = wsum;
    }
    __syncthreads();

    const float wn0 = wn_sh[0], wn1 = wn_sh[1], wn2 = wn_sh[2],
                wn3 = wn_sh[3], wn4 = wn_sh[4];
    const long i0 = seli_sh[0], i1 = seli_sh[1], i2 = seli_sh[2],
               i3 = seli_sh[3], i4 = seli_sh[4];

    // u[d] = sum_r wn_r * E[i_r][d]
    u_sh[t] = wn0 * E[i0*D_IN + t] + wn1 * E[i1*D_IN + t] + wn2 * E[i2*D_IN + t]
            + wn3 * E[i3*D_IN + t] + wn4 * E[i4*D_IN + t];
    __syncthreads();

    // h[j] = Wv[j].u + Wsum*bv[j]   (4 threads per row, quarter each)
    {
        const int j = t >> 2, qtr = t & 3;
        const f32x4* wrow = (const f32x4*)(Wv + (size_t)j * D_IN + qtr * 128);
        const f32x4* uv   = (const f32x4*)(u_sh + qtr * 128);
        float acc = 0.f;
        #pragma unroll 16
        for (int k = 0; k < 32; ++k) {
            f32x4 a = wrow[k], b = uv[k];
            acc += a.x*b.x + a.y*b.y + a.z*b.z + a.w*b.w;
        }
        hp[t] = acc;
    }
    __syncthreads();
    if (t < D_HID)
        h_sh[t] = (hp[4*t] + hp[4*t+1]) + (hp[4*t+2] + hp[4*t+3]) + Wsum_sh * bv[t];
    __syncthreads();

    // out: 8 rows per block, one per wave
    {
        const float2* hv = (const float2*)h_sh;
        const float2 hh = hv[l];
        const int o = blockIdx.x * 8 + w;
        const float2* orow = (const float2*)(Wo + (size_t)o * D_HID);
        float2 a = orow[l];
        float d = a.x*hh.x + a.y*hh.y;
        #pragma unroll
        for (int mm = 32; mm > 0; mm >>= 1) d += __shfl_xor(d, mm, 64);
        if (l == 0) out[o] = d + bo[o];
    }
}

extern "C" void kernel_launch(void* const* d_in, const int* in_sizes, int n_in,
                              void* d_out, int out_size, void* d_ws, size_t ws_size,
                              hipStream_t stream) {
    const float* c  = (const float*)d_in[0];
    const float* E  = (const float*)d_in[1];
    const float* Wq = (const float*)d_in[2];
    const float* bq = (const float*)d_in[3];
    const float* Wk = (const float*)d_in[4];
    // d_in[5] = bk: uniform logit shift, cancels in softmax
    const float* Wv = (const float*)d_in[6];
    const float* bv = (const float*)d_in[7];
    const float* Wo = (const float*)d_in[8];
    const float* bo = (const float*)d_in[9];
    // d_in[10] = top_k (always 5)
    float* ws  = (float*)d_ws;
    float* out = (float*)d_out;

    hipLaunchKernelGGL(k_front,  dim3(8),         dim3(512), 0, stream, c, Wq, bq, Wk, ws);
    hipLaunchKernelGGL(k_logits, dim3(K3_BLOCKS), dim3(256), 0, stream, E, ws);
    hipLaunchKernelGGL(k_vo,     dim3(64),        dim3(512), 0, stream,
                       E, Wv, bv, Wo, bo, ws, out);
}

// Round 9
// 130.784 us; speedup vs baseline: 1.0226x; 1.0226x over previous
//
#include <hip/hip_runtime.h>
#include <math.h>

#define D_IN 512
#define D_HID 128
#define D_OUT 512
#define N_ENT 262144

#define K3_BLOCKS 2048
#define WAVES_PER_BLOCK 4
#define TOTAL_WAVES (K3_BLOCKS * WAVES_PER_BLOCK)   // 8192
#define ROWS_PER_WAVE (N_ENT / TOTAL_WAVES)         // 32

// ws float-offsets
#define KV_OFF    0                // 512: kvec pre-scaled by 1/sqrt(H)
#define BS_OFF    512              // 2048 block sums of exp(logit)
#define BT5_OFF_F 2560             // byte 10240 (8B aligned): 2048*5 u64 keys

#define INV_SQRT_H 0.08838834764831845f  // 1/sqrt(128)

typedef float f32x4 __attribute__((ext_vector_type(4)));
typedef unsigned long long u64;

#define NTLD(p) __builtin_nontemporal_load(p)

__device__ inline u64 pack_key(float v, int idx) {
    unsigned u = __float_as_uint(v);
    u = (u & 0x80000000u) ? ~u : (u | 0x80000000u);   // order-preserving
    return ((u64)u << 32) | (unsigned)(~idx);          // ties -> smaller idx wins
}
__device__ inline float unpack_val(u64 k) {
    unsigned o = (unsigned)(k >> 32);
    unsigned u = (o & 0x80000000u) ? (o & 0x7FFFFFFFu) : ~o;
    return __uint_as_float(u);
}
__device__ inline int unpack_idx(u64 k) { return (int)~(unsigned)(k & 0xFFFFFFFFu); }

#define INS5(kk) do { u64 _k = (kk); if (_k > t4) {            \
    if (_k > t0)      { t4=t3;t3=t2;t2=t1;t1=t0;t0=_k; }       \
    else if (_k > t1) { t4=t3;t3=t2;t2=t1;t1=_k; }             \
    else if (_k > t2) { t4=t3;t3=t2;t2=_k; }                   \
    else if (_k > t3) { t4=t3;t3=_k; }                         \
    else              { t4=_k; } } } while (0)

// ---------- K1: fused front — q = Wq@c+bq (redundant/block), kvec slice ----------
__global__ __launch_bounds__(512) void k_front(const float* __restrict__ c,
        const float* __restrict__ Wq, const float* __restrict__ bq,
        const float* __restrict__ Wk, float* __restrict__ ws) {
    __shared__ float qpart[512];
    __shared__ float qs[D_HID];
    __shared__ float kpart[8][64];
    const int t = threadIdx.x;
    {   // phase 1: q, 4 threads per row (quarter-row each)
        const int row = t >> 2, qtr = t & 3;
        const f32x4* wq = (const f32x4*)(Wq + (size_t)row * D_IN + qtr * 128);
        const f32x4* cv = (const f32x4*)(c + qtr * 128);
        float acc = 0.f;
        #pragma unroll 16
        for (int j = 0; j < 32; ++j) {
            f32x4 a = wq[j], b = cv[j];
            acc += a.x*b.x + a.y*b.y + a.z*b.z + a.w*b.w;
        }
        qpart[t] = acc;
    }
    __syncthreads();
    if (t < D_HID) qs[t] = (qpart[4*t] + qpart[4*t+1]) + (qpart[4*t+2] + qpart[4*t+3]) + bq[t];
    __syncthreads();
    {   // phase 2: kvec[d0..d0+64), wave g covers h in [16g,16g+16)
        const int g = t >> 6, d = t & 63;
        const int d0 = blockIdx.x * 64;
        const float* col = Wk + (size_t)(g * 16) * D_IN + d0 + d;
        float acc = 0.f;
        #pragma unroll 16
        for (int h = 0; h < 16; ++h) acc += col[(size_t)h * D_IN] * qs[g*16 + h];
        kpart[g][d] = acc;
    }
    __syncthreads();
    if (t < 64) {
        float kv = ((kpart[0][t] + kpart[1][t]) + (kpart[2][t] + kpart[3][t]))
                 + ((kpart[4][t] + kpart[5][t]) + (kpart[6][t] + kpart[7][t]));
        ws[KV_OFF + blockIdx.x*64 + t] = kv * INV_SQRT_H;   // pre-scale
    }
}

// ---------- K2: logits + softmax-sum + per-block top5 ----------
// Minimal-VGPR 2-row loop: single lane-base pointer, imm offsets 0/1024/2048/3072,
// pointer bump 4096B/iter. __launch_bounds__(256,8) forces <=64 VGPR ->
// 8 waves/SIMD (32 waves/CU) for max read MLP. No online max (logits~N(0,1),
// direct exp-sum safe in fp32 to logit ~80; validated bit-exact in R8).
__global__ __launch_bounds__(256, 8) void k_logits(const float* __restrict__ E,
                                                   float* __restrict__ ws) {
    const int t = threadIdx.x;
    const int l = t & 63;
    const int w = t >> 6;
    const long row0 = ((long)blockIdx.x * WAVES_PER_BLOCK + w) * ROWS_PER_WAVE;

    const f32x4* kv = (const f32x4*)(ws + KV_OFF);
    const f32x4 k0 = kv[l], k1 = kv[64 + l];

    float s = 0.f;
    u64 t0 = 0, t1 = 0, t2 = 0, t3 = 0, t4 = 0;   // 0 < any real key

    const f32x4* rp = (const f32x4*)(E + row0 * (long)D_IN) + l;
    for (int it = 0; it < ROWS_PER_WAVE; it += 2, rp += 256) {
        f32x4 a0 = NTLD(rp);          // row it,   bytes [l*16 .. )
        f32x4 a1 = NTLD(rp + 64);     // row it,   +1024B
        f32x4 b0 = NTLD(rp + 128);    // row it+1, +2048B
        f32x4 b1 = NTLD(rp + 192);    // row it+1, +3072B
        float d0 = a0.x*k0.x + a0.y*k0.y + a0.z*k0.z + a0.w*k0.w
                 + a1.x*k1.x + a1.y*k1.y + a1.z*k1.z + a1.w*k1.w;
        float d1 = b0.x*k0.x + b0.y*k0.y + b0.z*k0.z + b0.w*k0.w
                 + b1.x*k1.x + b1.y*k1.y + b1.z*k1.z + b1.w*k1.w;
        #pragma unroll
        for (int mm = 32; mm > 0; mm >>= 1) {   // two independent chains, ILP
            d0 += __shfl_xor(d0, mm, 64);
            d1 += __shfl_xor(d1, mm, 64);
        }
        s += __expf(d0) + __expf(d1);
        INS5(pack_key(d0, (int)row0 + it));
        INS5(pack_key(d1, (int)row0 + it + 1));
    }

    __shared__ float ss[WAVES_PER_BLOCK];
    __shared__ u64 skey[WAVES_PER_BLOCK][5];
    if (l == 0) {
        ss[w] = s;
        skey[w][0]=t0; skey[w][1]=t1; skey[w][2]=t2; skey[w][3]=t3; skey[w][4]=t4;
    }
    __syncthreads();
    if (t == 0) {
        float S = (ss[0] + ss[1]) + (ss[2] + ss[3]);
        u64 t0=0,t1=0,t2=0,t3=0,t4=0;
        #pragma unroll
        for (int j = 0; j < WAVES_PER_BLOCK*5; ++j) INS5(skey[j/5][j%5]);
        const int b = blockIdx.x;
        ws[BS_OFF + b] = S;
        u64* bt = (u64*)ws + (BT5_OFF_F/2) + (size_t)b * 5;
        bt[0]=t0; bt[1]=t1; bt[2]=t2; bt[3]=t3; bt[4]=t4;
    }
}

// ---------- K3: redundant merge + u -> h -> out  (64 blocks x 512) ----------
__global__ __launch_bounds__(512) void k_vo(const float* __restrict__ E,
        const float* __restrict__ Wv, const float* __restrict__ bv,
        const float* __restrict__ Wo, const float* __restrict__ bo,
        const float* __restrict__ ws, float* __restrict__ out) {
    __shared__ u64   mwc[8][5];
    __shared__ float selv_sh[5];
    __shared__ int   seli_sh[5];
    __shared__ float wn_sh[5];
    __shared__ float zp[8];
    __shared__ float Wsum_sh;
    __shared__ float u_sh[D_IN];
    __shared__ float hp[512];
    __shared__ float h_sh[D_HID];
    const int t = threadIdx.x;
    const int l = t & 63;
    const int w = t >> 6;
    const u64* cand = (const u64*)ws + (BT5_OFF_F/2);

    // per-thread top5 over 20 candidates each (10240 total)
    u64 t0=0,t1=0,t2=0,t3=0,t4=0;
    #pragma unroll 4
    for (int j = 0; j < 20; ++j) INS5(cand[t + 512*j]);

    // wave top5: 5 rounds of extract-max
    {
        int pos = 0;
        u64 g0=0,g1=0,g2=0,g3=0,g4=0;
        #pragma unroll
        for (int r = 0; r < 5; ++r) {
            u64 head = pos==0?t0 : pos==1?t1 : pos==2?t2 : pos==3?t3 : pos==4?t4 : 0ULL;
            u64 wm = head;
            #pragma unroll
            for (int mm = 1; mm < 64; mm <<= 1) {
                u64 o = __shfl_xor(wm, mm, 64);
                wm = (o > wm) ? o : wm;
            }
            if (head == wm && wm != 0ULL) pos++;
            if (r==0) g0=wm; else if (r==1) g1=wm; else if (r==2) g2=wm;
            else if (r==3) g3=wm; else g4=wm;
        }
        if (l == 0) { mwc[w][0]=g0; mwc[w][1]=g1; mwc[w][2]=g2; mwc[w][3]=g3; mwc[w][4]=g4; }
    }
    __syncthreads();

    // cross-wave merge on wave 0 (lanes 0..7 present list heads)
    if (w == 0) {
        int pos = 0;
        #pragma unroll
        for (int r = 0; r < 5; ++r) {
            u64 head = (l < 8 && pos < 5) ? mwc[l][pos] : 0ULL;
            u64 wm = head;
            #pragma unroll
            for (int mm = 1; mm < 64; mm <<= 1) {
                u64 o = __shfl_xor(wm, mm, 64);
                wm = (o > wm) ? o : wm;
            }
            if (head == wm && wm != 0ULL) pos++;
            if (l == 0) { selv_sh[r] = unpack_val(wm); seli_sh[r] = unpack_idx(wm); }
        }
    }
    __syncthreads();

    // Z = sum_b S_b (no rescale; see k_logits comment)
    {
        float z = 0.f;
        #pragma unroll
        for (int k = 0; k < K3_BLOCKS/512; ++k) z += ws[BS_OFF + t + 512*k];
        #pragma unroll
        for (int mm = 1; mm < 64; mm <<= 1) z += __shfl_xor(z, mm, 64);
        if (l == 0) zp[w] = z;
    }
    __syncthreads();
    if (t == 0) {
        float Z = ((zp[0]+zp[1]) + (zp[2]+zp[3])) + ((zp[4]+zp[5]) + (zp[6]+zp[7]));
        float wsum = 0.f;
        #pragma unroll
        for (int r = 0; r < 5; ++r) {
            float wv = __expf(selv_sh[r]) / Z;
            wn_sh[r] = wv;
            wsum += wv;
        }
        Wsum_sh = wsum;
    }
    __syncthreads();

    const float wn0 = wn_sh[0], wn1 = wn_sh[1], wn2 = wn_sh[2],
                wn3 = wn_sh[3], wn4 = wn_sh[4];
    const long i0 = seli_sh[0], i1 = seli_sh[1], i2 = seli_sh[2],
               i3 = seli_sh[3], i4 = seli_sh[4];

    // u[d] = sum_r wn_r * E[i_r][d]
    u_sh[t] = wn0 * E[i0*D_IN + t] + wn1 * E[i1*D_IN + t] + wn2 * E[i2*D_IN + t]
            + wn3 * E[i3*D_IN + t] + wn4 * E[i4*D_IN + t];
    __syncthreads();

    // h[j] = Wv[j].u + Wsum*bv[j]   (4 threads per row, quarter each)
    {
        const int j = t >> 2, qtr = t & 3;
        const f32x4* wrow = (const f32x4*)(Wv + (size_t)j * D_IN + qtr * 128);
        const f32x4* uv   = (const f32x4*)(u_sh + qtr * 128);
        float acc = 0.f;
        #pragma unroll 16
        for (int k = 0; k < 32; ++k) {
            f32x4 a = wrow[k], b = uv[k];
            acc += a.x*b.x + a.y*b.y + a.z*b.z + a.w*b.w;
        }
        hp[t] = acc;
    }
    __syncthreads();
    if (t < D_HID)
        h_sh[t] = (hp[4*t] + hp[4*t+1]) + (hp[4*t+2] + hp[4*t+3]) + Wsum_sh * bv[t];
    __syncthreads();

    // out: 8 rows per block, one per wave
    {
        const float2* hv = (const float2*)h_sh;
        const float2 hh = hv[l];
        const int o = blockIdx.x * 8 + w;
        const float2* orow = (const float2*)(Wo + (size_t)o * D_HID);
        float2 a = orow[l];
        float d = a.x*hh.x + a.y*hh.y;
        #pragma unroll
        for (int mm = 32; mm > 0; mm >>= 1) d += __shfl_xor(d, mm, 64);
        if (l == 0) out[o] = d + bo[o];
    }
}

extern "C" void kernel_launch(void* const* d_in, const int* in_sizes, int n_in,
                              void* d_out, int out_size, void* d_ws, size_t ws_size,
                              hipStream_t stream) {
    const float* c  = (const float*)d_in[0];
    const float* E  = (const float*)d_in[1];
    const float* Wq = (const float*)d_in[2];
    const float* bq = (const float*)d_in[3];
    const float* Wk = (const float*)d_in[4];
    // d_in[5] = bk: uniform logit shift, cancels in softmax
    const float* Wv = (const float*)d_in[6];
    const float* bv = (const float*)d_in[7];
    const float* Wo = (const float*)d_in[8];
    const float* bo = (const float*)d_in[9];
    // d_in[10] = top_k (always 5)
    float* ws  = (float*)d_ws;
    float* out = (float*)d_out;

    hipLaunchKernelGGL(k_front,  dim3(8),         dim3(512), 0, stream, c, Wq, bq, Wk, ws);
    hipLaunchKernelGGL(k_logits, dim3(K3_BLOCKS), dim3(256), 0, stream, E, ws);
    hipLaunchKernelGGL(k_vo,     dim3(64),        dim3(512), 0, stream,
                       E, Wv, bv, Wo, bo, ws, out);
}

// Round 10
// 120.793 us; speedup vs baseline: 1.1072x; 1.0827x over previous
//
#include <hip/hip_runtime.h>
#include <math.h>

#define D_IN 512
#define D_HID 128
#define D_OUT 512
#define N_ENT 262144

#define K3_BLOCKS 2048
#define WAVES_PER_BLOCK 4
#define TOTAL_WAVES (K3_BLOCKS * WAVES_PER_BLOCK)   // 8192
#define ROWS_PER_WAVE (N_ENT / TOTAL_WAVES)         // 32

// ws float-offsets
#define KV_OFF   0                // 512 floats: kvec pre-scaled by 1/sqrt(H)
#define BM_OFF   512              // 2048 block maxes
#define BS_OFF   2560             // 2048 block sums
#define BT5_OFF_F 4608            // byte 18432 (8B aligned): 2048*5 u64 keys
#define U_OFF    25088            // 512 floats (16B aligned)
#define W_OFF    25600            // 1 float: sum of top5 normalized scores
#define H_OFF    25604            // 128 floats (8B aligned)

#define INV_SQRT_H 0.08838834764831845f  // 1/sqrt(128)

typedef float f32x4 __attribute__((ext_vector_type(4)));
typedef unsigned long long u64;

__device__ inline u64 pack_key(float v, int idx) {
    unsigned u = __float_as_uint(v);
    u = (u & 0x80000000u) ? ~u : (u | 0x80000000u);   // order-preserving
    return ((u64)u << 32) | (unsigned)(~idx);          // ties -> smaller idx wins
}
__device__ inline float unpack_val(u64 k) {
    unsigned o = (unsigned)(k >> 32);
    unsigned u = (o & 0x80000000u) ? (o & 0x7FFFFFFFu) : ~o;
    return __uint_as_float(u);
}
__device__ inline int unpack_idx(u64 k) { return (int)~(unsigned)(k & 0xFFFFFFFFu); }

#define INS5(kk) do { u64 _k = (kk); if (_k > t4) {            \
    if (_k > t0)      { t4=t3;t3=t2;t2=t1;t1=t0;t0=_k; }       \
    else if (_k > t1) { t4=t3;t3=t2;t2=t1;t1=_k; }             \
    else if (_k > t2) { t4=t3;t3=t2;t2=_k; }                   \
    else if (_k > t3) { t4=t3;t3=_k; }                         \
    else              { t4=_k; } } } while (0)

// ---------- K1: fused q = Wq@c+bq (redundant/block) + kvec chunk ----------
__global__ __launch_bounds__(256) void k_front(const float* __restrict__ c,
        const float* __restrict__ Wq, const float* __restrict__ bq,
        const float* __restrict__ Wk, float* __restrict__ ws) {
    __shared__ float qpart[256];
    __shared__ float qs[D_HID];
    __shared__ float kpart[4][64];
    const int t = threadIdx.x;
    {   // phase 1: q[128], 2 threads per h
        const int h = t >> 1, half = t & 1;
        const f32x4* wq = (const f32x4*)(Wq + (h << 9) + (half << 8));
        const f32x4* cv = (const f32x4*)(c + (half << 8));
        float acc = 0.f;
        #pragma unroll 8
        for (int j = 0; j < 64; ++j) {
            f32x4 a = wq[j], b = cv[j];
            acc += a.x*b.x + a.y*b.y + a.z*b.z + a.w*b.w;
        }
        qpart[t] = acc;
    }
    __syncthreads();
    if (t < D_HID) qs[t] = qpart[2*t] + qpart[2*t+1] + bq[t];
    __syncthreads();
    {   // phase 2: kvec[d0..d0+64), wave g covers h in [32g,32g+32)
        const int g = t >> 6, d = t & 63;
        const int d0 = blockIdx.x * 64;
        const float* col = Wk + (size_t)(g * 32) * D_IN + d0 + d;
        float acc = 0.f;
        #pragma unroll 8
        for (int h = 0; h < 32; ++h) acc += col[(size_t)h * D_IN] * qs[g*32 + h];
        kpart[g][d] = acc;
    }
    __syncthreads();
    if (t < 64) {
        float kv = kpart[0][t] + kpart[1][t] + kpart[2][t] + kpart[3][t];
        ws[KV_OFF + blockIdx.x*64 + t] = kv * INV_SQRT_H;   // pre-scale
    }
}

// ---------- K2: logits + online softmax + per-block top5 (packed u64) ----------
__global__ __launch_bounds__(256) void k_logits(const float* __restrict__ E,
                                                float* __restrict__ ws) {
    const int t = threadIdx.x;
    const int l = t & 63;
    const int w = t >> 6;
    const int wg = blockIdx.x * WAVES_PER_BLOCK + w;
    const long row0 = (long)wg * ROWS_PER_WAVE;

    const f32x4* kv = (const f32x4*)(ws + KV_OFF);
    const f32x4 k0 = kv[l], k1 = kv[64 + l];

    float m = -INFINITY, s = 0.f;
    u64 t0 = 0, t1 = 0, t2 = 0, t3 = 0, t4 = 0;   // 0 < any real key

    for (int it = 0; it < ROWS_PER_WAVE; it += 2) {
        const f32x4* r0 = (const f32x4*)(E + (row0 + it)     * (long)D_IN);
        const f32x4* r1 = (const f32x4*)(E + (row0 + it + 1) * (long)D_IN);
        f32x4 a0 = __builtin_nontemporal_load(r0 + l);
        f32x4 a1 = __builtin_nontemporal_load(r0 + 64 + l);
        f32x4 b0 = __builtin_nontemporal_load(r1 + l);
        f32x4 b1 = __builtin_nontemporal_load(r1 + 64 + l);
        float d0 = a0.x*k0.x + a0.y*k0.y + a0.z*k0.z + a0.w*k0.w
                 + a1.x*k1.x + a1.y*k1.y + a1.z*k1.z + a1.w*k1.w;
        float d1 = b0.x*k0.x + b0.y*k0.y + b0.z*k0.z + b0.w*k0.w
                 + b1.x*k1.x + b1.y*k1.y + b1.z*k1.z + b1.w*k1.w;
        #pragma unroll
        for (int mm = 32; mm > 0; mm >>= 1) {   // two independent chains, ILP
            d0 += __shfl_xor(d0, mm, 64);
            d1 += __shfl_xor(d1, mm, 64);
        }
        // kvec pre-scaled: d0/d1 ARE the logits
        float nm = fmaxf(m, fmaxf(d0, d1));
        s = s * __expf(m - nm) + __expf(d0 - nm) + __expf(d1 - nm);
        m = nm;
        INS5(pack_key(d0, (int)row0 + it));
        INS5(pack_key(d1, (int)row0 + it + 1));
    }

    __shared__ float sm[WAVES_PER_BLOCK], ss[WAVES_PER_BLOCK];
    __shared__ u64 skey[WAVES_PER_BLOCK][5];
    if (l == 0) {
        sm[w] = m; ss[w] = s;
        skey[w][0]=t0; skey[w][1]=t1; skey[w][2]=t2; skey[w][3]=t3; skey[w][4]=t4;
    }
    __syncthreads();
    if (t == 0) {
        float M = fmaxf(fmaxf(sm[0], sm[1]), fmaxf(sm[2], sm[3]));
        float S = ss[0]*__expf(sm[0]-M) + ss[1]*__expf(sm[1]-M)
                + ss[2]*__expf(sm[2]-M) + ss[3]*__expf(sm[3]-M);
        u64 t0=0,t1=0,t2=0,t3=0,t4=0;
        #pragma unroll
        for (int j = 0; j < WAVES_PER_BLOCK*5; ++j) INS5(skey[j/5][j%5]);
        const int b = blockIdx.x;
        ws[BM_OFF + b] = M;
        ws[BS_OFF + b] = S;
        u64* bt = (u64*)ws + (BT5_OFF_F/2) + (size_t)b * 5;
        bt[0]=t0; bt[1]=t1; bt[2]=t2; bt[3]=t3; bt[4]=t4;
    }
}

// ---------- K3: global top5 -> M -> Z -> weights -> u  (1 block x 1024) ----------
__global__ __launch_bounds__(1024) void k_mid(const float* __restrict__ E,
                                              float* __restrict__ ws) {
    __shared__ u64   wc[16][5];
    __shared__ float selv[5];
    __shared__ int   seli[5];
    __shared__ float wn[5];
    __shared__ float zp[16];
    __shared__ float Zsh;
    const int t = threadIdx.x;
    const int l = t & 63;
    const int w = t >> 6;
    const u64* cand = (const u64*)ws + (BT5_OFF_F/2);

    // local top5 over 10 candidates
    u64 t0=0,t1=0,t2=0,t3=0,t4=0;
    #pragma unroll
    for (int j = 0; j < 10; ++j) INS5(cand[t + j*1024]);

    // wave top5: 5 rounds of extract-max (keys unique -> exactly one advancer)
    {
        int pos = 0;
        u64 g0=0,g1=0,g2=0,g3=0,g4=0;
        #pragma unroll
        for (int r = 0; r < 5; ++r) {
            u64 head = pos==0?t0 : pos==1?t1 : pos==2?t2 : pos==3?t3 : pos==4?t4 : 0ULL;
            u64 wm = head;
            #pragma unroll
            for (int mm = 1; mm < 64; mm <<= 1) {
                u64 o = __shfl_xor(wm, mm, 64);
                wm = (o > wm) ? o : wm;
            }
            if (head == wm && wm != 0ULL) pos++;
            if (r==0) g0=wm; else if (r==1) g1=wm; else if (r==2) g2=wm;
            else if (r==3) g3=wm; else g4=wm;
        }
        if (l == 0) { wc[w][0]=g0; wc[w][1]=g1; wc[w][2]=g2; wc[w][3]=g3; wc[w][4]=g4; }
    }
    __syncthreads();

    // cross-wave merge (wave 0; lanes 0..15 present list heads)
    if (t < 64) {
        int pos = 0;
        #pragma unroll
        for (int r = 0; r < 5; ++r) {
            u64 head = (t < 16 && pos < 5) ? wc[t][pos] : 0ULL;
            u64 wm = head;
            #pragma unroll
            for (int mm = 1; mm < 64; mm <<= 1) {
                u64 o = __shfl_xor(wm, mm, 64);
                wm = (o > wm) ? o : wm;
            }
            if (head == wm && wm != 0ULL) pos++;
            if (t == 0) { selv[r] = unpack_val(wm); seli[r] = unpack_idx(wm); }
        }
    }
    __syncthreads();

    const float M = selv[0];   // global max logit == top-1 value

    // Z = sum over blocks of S_b * exp(M_b - M)
    {
        float z = ws[BS_OFF + t]      * __expf(ws[BM_OFF + t]      - M)
                + ws[BS_OFF + t+1024] * __expf(ws[BM_OFF + t+1024] - M);
        #pragma unroll
        for (int mm = 1; mm < 64; mm <<= 1) z += __shfl_xor(z, mm, 64);
        if (l == 0) zp[w] = z;
    }
    __syncthreads();
    if (t == 0) {
        float Z = 0.f;
        #pragma unroll
        for (int j = 0; j < 16; ++j) Z += zp[j];
        Zsh = Z;
    }
    __syncthreads();
    if (t < 8) {
        float Z = Zsh;
        if (t < 5) wn[t] = __expf(selv[t] - M) / Z;
    }
    __syncthreads();
    if (t == 0) ws[W_OFF] = wn[0]+wn[1]+wn[2]+wn[3]+wn[4];

    // u[d] = sum_r wn[r] * E[idx_r][d]
    if (t < D_IN) {
        float acc = 0.f;
        #pragma unroll
        for (int r = 0; r < 5; ++r)
            acc += wn[r] * E[(long)seli[r] * D_IN + t];
        ws[U_OFF + t] = acc;
    }
}

// ---------- K4: h = Wv @ u + W*bv  (128 blocks x 64) ----------
__global__ void k_h(const float* __restrict__ Wv, const float* __restrict__ bv,
                    float* __restrict__ ws) {
    const int j = blockIdx.x;
    const int l = threadIdx.x;
    const f32x4* row = (const f32x4*)(Wv + (size_t)j * D_IN);
    const f32x4* u   = (const f32x4*)(ws + U_OFF);
    f32x4 a0 = row[l], a1 = row[64 + l];
    f32x4 u0 = u[l],   u1 = u[64 + l];
    float d = a0.x*u0.x + a0.y*u0.y + a0.z*u0.z + a0.w*u0.w
            + a1.x*u1.x + a1.y*u1.y + a1.z*u1.z + a1.w*u1.w;
    #pragma unroll
    for (int m = 32; m > 0; m >>= 1) d += __shfl_xor(d, m, 64);
    if (l == 0) ws[H_OFF + j] = d + ws[W_OFF] * bv[j];
}

// ---------- K5: out = Wo @ h + bo  (512 blocks x 64) ----------
__global__ void k_out(const float* __restrict__ Wo, const float* __restrict__ bo,
                      const float* __restrict__ ws, float* __restrict__ out) {
    const int o = blockIdx.x;
    const int l = threadIdx.x;
    const float2* row = (const float2*)(Wo + (size_t)o * D_HID);
    const float2* h   = (const float2*)(ws + H_OFF);
    float2 a = row[l], hh = h[l];
    float d = a.x*hh.x + a.y*hh.y;
    #pragma unroll
    for (int m = 32; m > 0; m >>= 1) d += __shfl_xor(d, m, 64);
    if (l == 0) out[o] = d + bo[o];
}

extern "C" void kernel_launch(void* const* d_in, const int* in_sizes, int n_in,
                              void* d_out, int out_size, void* d_ws, size_t ws_size,
                              hipStream_t stream) {
    const float* c  = (const float*)d_in[0];
    const float* E  = (const float*)d_in[1];
    const float* Wq = (const float*)d_in[2];
    const float* bq = (const float*)d_in[3];
    const float* Wk = (const float*)d_in[4];
    // d_in[5] = bk: uniform logit shift, cancels in softmax
    const float* Wv = (const float*)d_in[6];
    const float* bv = (const float*)d_in[7];
    const float* Wo = (const float*)d_in[8];
    const float* bo = (const float*)d_in[9];
    // d_in[10] = top_k (always 5)
    float* ws  = (float*)d_ws;
    float* out = (float*)d_out;

    hipLaunchKernelGGL(k_front,  dim3(8),         dim3(256),  0, stream, c, Wq, bq, Wk, ws);
    hipLaunchKernelGGL(k_logits, dim3(K3_BLOCKS), dim3(256),  0, stream, E, ws);
    hipLaunchKernelGGL(k_mid,    dim3(1),         dim3(1024), 0, stream, E, ws);
    hipLaunchKernelGGL(k_h,      dim3(128),       dim3(64),   0, stream, Wv, bv, ws);
    hipLaunchKernelGGL(k_out,    dim3(512),       dim3(64),   0, stream, Wo, bo, ws, out);
}

// Round 11
// 111.854 us; speedup vs baseline: 1.1956x; 1.0799x over previous
//
#include <hip/hip_runtime.h>
#include <math.h>

#define D_IN 512
#define D_HID 128
#define D_OUT 512
#define N_ENT 262144

#define K3_BLOCKS 2048
#define WAVES_PER_BLOCK 4
#define ROWS_PER_BLOCK 128          // N_ENT / K3_BLOCKS
#define PAIRS_PER_WAVE 16           // 32 rows per wave, 2 per iteration

// ws float-offsets
#define KV_OFF   0                // 512 floats: kvec pre-scaled by 1/sqrt(H)
#define BM_OFF   512              // 2048 block maxes
#define BS_OFF   2560             // 2048 block sums
#define BT5_OFF_F 4608            // byte 18432 (8B aligned): 2048*5 u64 keys
#define U_OFF    25088            // 512 floats (16B aligned)
#define W_OFF    25600            // 1 float: sum of top5 normalized scores
#define H_OFF    25604            // 128 floats (8B aligned)

#define INV_SQRT_H 0.08838834764831845f  // 1/sqrt(128)

typedef float f32x4 __attribute__((ext_vector_type(4)));
typedef unsigned long long u64;

__device__ inline u64 pack_key(float v, int idx) {
    unsigned u = __float_as_uint(v);
    u = (u & 0x80000000u) ? ~u : (u | 0x80000000u);   // order-preserving
    return ((u64)u << 32) | (unsigned)(~idx);          // ties -> smaller idx wins
}
__device__ inline float unpack_val(u64 k) {
    unsigned o = (unsigned)(k >> 32);
    unsigned u = (o & 0x80000000u) ? (o & 0x7FFFFFFFu) : ~o;
    return __uint_as_float(u);
}
__device__ inline int unpack_idx(u64 k) { return (int)~(unsigned)(k & 0xFFFFFFFFu); }

#define INS5(kk) do { u64 _k = (kk); if (_k > t4) {            \
    if (_k > t0)      { t4=t3;t3=t2;t2=t1;t1=t0;t0=_k; }       \
    else if (_k > t1) { t4=t3;t3=t2;t2=t1;t1=_k; }             \
    else if (_k > t2) { t4=t3;t3=t2;t2=_k; }                   \
    else if (_k > t3) { t4=t3;t3=_k; }                         \
    else              { t4=_k; } } } while (0)

// ---------- K1: fused q = Wq@c+bq (redundant/block) + kvec chunk ----------
__global__ __launch_bounds__(256) void k_front(const float* __restrict__ c,
        const float* __restrict__ Wq, const float* __restrict__ bq,
        const float* __restrict__ Wk, float* __restrict__ ws) {
    __shared__ float qpart[256];
    __shared__ float qs[D_HID];
    __shared__ float kpart[4][64];
    const int t = threadIdx.x;
    {   // phase 1: q[128], 2 threads per h
        const int h = t >> 1, half = t & 1;
        const f32x4* wq = (const f32x4*)(Wq + (h << 9) + (half << 8));
        const f32x4* cv = (const f32x4*)(c + (half << 8));
        float acc = 0.f;
        #pragma unroll 8
        for (int j = 0; j < 64; ++j) {
            f32x4 a = wq[j], b = cv[j];
            acc += a.x*b.x + a.y*b.y + a.z*b.z + a.w*b.w;
        }
        qpart[t] = acc;
    }
    __syncthreads();
    if (t < D_HID) qs[t] = qpart[2*t] + qpart[2*t+1] + bq[t];
    __syncthreads();
    {   // phase 2: kvec[d0..d0+64), wave g covers h in [32g,32g+32)
        const int g = t >> 6, d = t & 63;
        const int d0 = blockIdx.x * 64;
        const float* col = Wk + (size_t)(g * 32) * D_IN + d0 + d;
        float acc = 0.f;
        #pragma unroll 8
        for (int h = 0; h < 32; ++h) acc += col[(size_t)h * D_IN] * qs[g*32 + h];
        kpart[g][d] = acc;
    }
    __syncthreads();
    if (t < 64) {
        float kv = kpart[0][t] + kpart[1][t] + kpart[2][t] + kpart[3][t];
        ws[KV_OFF + blockIdx.x*64 + t] = kv * INV_SQRT_H;   // pre-scale
    }
}

// ---------- K2: logits + online softmax + per-block top5 (packed u64) ----------
// Row->wave mapping interleaved WITHIN the block: wave w takes row pairs
// base + 2w + 8k. At any instant the block's 4 waves read 8 contiguous rows
// (16 KB burst) instead of 4 points spread over 256 KB -> 2048 sequential
// streams instead of 8192 scattered ones (DRAM page-locality experiment).
__global__ __launch_bounds__(256) void k_logits(const float* __restrict__ E,
                                                float* __restrict__ ws) {
    const int t = threadIdx.x;
    const int l = t & 63;
    const int w = t >> 6;
    const long base = (long)blockIdx.x * ROWS_PER_BLOCK;
    const long r0   = base + 2 * w;             // this wave's first row

    const f32x4* kv = (const f32x4*)(ws + KV_OFF);
    const f32x4 k0 = kv[l], k1 = kv[64 + l];

    float m = -INFINITY, s = 0.f;
    u64 t0 = 0, t1 = 0, t2 = 0, t3 = 0, t4 = 0;   // 0 < any real key

    const f32x4* rp = (const f32x4*)(E + r0 * (long)D_IN) + l;
    for (int k = 0; k < PAIRS_PER_WAVE; ++k, rp += 1024) {   // +8 rows/iter
        f32x4 a0 = __builtin_nontemporal_load(rp);
        f32x4 a1 = __builtin_nontemporal_load(rp + 64);
        f32x4 b0 = __builtin_nontemporal_load(rp + 128);
        f32x4 b1 = __builtin_nontemporal_load(rp + 192);
        float d0 = a0.x*k0.x + a0.y*k0.y + a0.z*k0.z + a0.w*k0.w
                 + a1.x*k1.x + a1.y*k1.y + a1.z*k1.z + a1.w*k1.w;
        float d1 = b0.x*k0.x + b0.y*k0.y + b0.z*k0.z + b0.w*k0.w
                 + b1.x*k1.x + b1.y*k1.y + b1.z*k1.z + b1.w*k1.w;
        #pragma unroll
        for (int mm = 32; mm > 0; mm >>= 1) {   // two independent chains, ILP
            d0 += __shfl_xor(d0, mm, 64);
            d1 += __shfl_xor(d1, mm, 64);
        }
        // kvec pre-scaled: d0/d1 ARE the logits
        float nm = fmaxf(m, fmaxf(d0, d1));
        s = s * __expf(m - nm) + __expf(d0 - nm) + __expf(d1 - nm);
        m = nm;
        const int idx = (int)r0 + 8 * k;
        INS5(pack_key(d0, idx));
        INS5(pack_key(d1, idx + 1));
    }

    __shared__ float sm[WAVES_PER_BLOCK], ss[WAVES_PER_BLOCK];
    __shared__ u64 skey[WAVES_PER_BLOCK][5];
    if (l == 0) {
        sm[w] = m; ss[w] = s;
        skey[w][0]=t0; skey[w][1]=t1; skey[w][2]=t2; skey[w][3]=t3; skey[w][4]=t4;
    }
    __syncthreads();
    if (t == 0) {
        float M = fmaxf(fmaxf(sm[0], sm[1]), fmaxf(sm[2], sm[3]));
        float S = ss[0]*__expf(sm[0]-M) + ss[1]*__expf(sm[1]-M)
                + ss[2]*__expf(sm[2]-M) + ss[3]*__expf(sm[3]-M);
        u64 t0=0,t1=0,t2=0,t3=0,t4=0;
        #pragma unroll
        for (int j = 0; j < WAVES_PER_BLOCK*5; ++j) INS5(skey[j/5][j%5]);
        const int b = blockIdx.x;
        ws[BM_OFF + b] = M;
        ws[BS_OFF + b] = S;
        u64* bt = (u64*)ws + (BT5_OFF_F/2) + (size_t)b * 5;
        bt[0]=t0; bt[1]=t1; bt[2]=t2; bt[3]=t3; bt[4]=t4;
    }
}

// ---------- K3: global top5 -> M -> Z -> weights -> u  (1 block x 1024) ----------
__global__ __launch_bounds__(1024) void k_mid(const float* __restrict__ E,
                                              float* __restrict__ ws) {
    __shared__ u64   wc[16][5];
    __shared__ float selv[5];
    __shared__ int   seli[5];
    __shared__ float wn[5];
    __shared__ float zp[16];
    __shared__ float Zsh;
    const int t = threadIdx.x;
    const int l = t & 63;
    const int w = t >> 6;
    const u64* cand = (const u64*)ws + (BT5_OFF_F/2);

    // local top5 over 10 candidates
    u64 t0=0,t1=0,t2=0,t3=0,t4=0;
    #pragma unroll
    for (int j = 0; j < 10; ++j) INS5(cand[t + j*1024]);

    // wave top5: 5 rounds of extract-max (keys unique -> exactly one advancer)
    {
        int pos = 0;
        u64 g0=0,g1=0,g2=0,g3=0,g4=0;
        #pragma unroll
        for (int r = 0; r < 5; ++r) {
            u64 head = pos==0?t0 : pos==1?t1 : pos==2?t2 : pos==3?t3 : pos==4?t4 : 0ULL;
            u64 wm = head;
            #pragma unroll
            for (int mm = 1; mm < 64; mm <<= 1) {
                u64 o = __shfl_xor(wm, mm, 64);
                wm = (o > wm) ? o : wm;
            }
            if (head == wm && wm != 0ULL) pos++;
            if (r==0) g0=wm; else if (r==1) g1=wm; else if (r==2) g2=wm;
            else if (r==3) g3=wm; else g4=wm;
        }
        if (l == 0) { wc[w][0]=g0; wc[w][1]=g1; wc[w][2]=g2; wc[w][3]=g3; wc[w][4]=g4; }
    }
    __syncthreads();

    // cross-wave merge (wave 0; lanes 0..15 present list heads)
    if (t < 64) {
        int pos = 0;
        #pragma unroll
        for (int r = 0; r < 5; ++r) {
            u64 head = (t < 16 && pos < 5) ? wc[t][pos] : 0ULL;
            u64 wm = head;
            #pragma unroll
            for (int mm = 1; mm < 64; mm <<= 1) {
                u64 o = __shfl_xor(wm, mm, 64);
                wm = (o > wm) ? o : wm;
            }
            if (head == wm && wm != 0ULL) pos++;
            if (t == 0) { selv[r] = unpack_val(wm); seli[r] = unpack_idx(wm); }
        }
    }
    __syncthreads();

    const float M = selv[0];   // global max logit == top-1 value

    // Z = sum over blocks of S_b * exp(M_b - M)
    {
        float z = ws[BS_OFF + t]      * __expf(ws[BM_OFF + t]      - M)
                + ws[BS_OFF + t+1024] * __expf(ws[BM_OFF + t+1024] - M);
        #pragma unroll
        for (int mm = 1; mm < 64; mm <<= 1) z += __shfl_xor(z, mm, 64);
        if (l == 0) zp[w] = z;
    }
    __syncthreads();
    if (t == 0) {
        float Z = 0.f;
        #pragma unroll
        for (int j = 0; j < 16; ++j) Z += zp[j];
        Zsh = Z;
    }
    __syncthreads();
    if (t < 8) {
        float Z = Zsh;
        if (t < 5) wn[t] = __expf(selv[t] - M) / Z;
    }
    __syncthreads();
    if (t == 0) ws[W_OFF] = wn[0]+wn[1]+wn[2]+wn[3]+wn[4];

    // u[d] = sum_r wn[r] * E[idx_r][d]
    if (t < D_IN) {
        float acc = 0.f;
        #pragma unroll
        for (int r = 0; r < 5; ++r)
            acc += wn[r] * E[(long)seli[r] * D_IN + t];
        ws[U_OFF + t] = acc;
    }
}

// ---------- K4: h = Wv @ u + W*bv  (128 blocks x 64) ----------
__global__ void k_h(const float* __restrict__ Wv, const float* __restrict__ bv,
                    float* __restrict__ ws) {
    const int j = blockIdx.x;
    const int l = threadIdx.x;
    const f32x4* row = (const f32x4*)(Wv + (size_t)j * D_IN);
    const f32x4* u   = (const f32x4*)(ws + U_OFF);
    f32x4 a0 = row[l], a1 = row[64 + l];
    f32x4 u0 = u[l],   u1 = u[64 + l];
    float d = a0.x*u0.x + a0.y*u0.y + a0.z*u0.z + a0.w*u0.w
            + a1.x*u1.x + a1.y*u1.y + a1.z*u1.z + a1.w*u1.w;
    #pragma unroll
    for (int m = 32; m > 0; m >>= 1) d += __shfl_xor(d, m, 64);
    if (l == 0) ws[H_OFF + j] = d + ws[W_OFF] * bv[j];
}

// ---------- K5: out = Wo @ h + bo  (512 blocks x 64) ----------
__global__ void k_out(const float* __restrict__ Wo, const float* __restrict__ bo,
                      const float* __restrict__ ws, float* __restrict__ out) {
    const int o = blockIdx.x;
    const int l = threadIdx.x;
    const float2* row = (const float2*)(Wo + (size_t)o * D_HID);
    const float2* h   = (const float2*)(ws + H_OFF);
    float2 a = row[l], hh = h[l];
    float d = a.x*hh.x + a.y*hh.y;
    #pragma unroll
    for (int m = 32; m > 0; m >>= 1) d += __shfl_xor(d, m, 64);
    if (l == 0) out[o] = d + bo[o];
}

extern "C" void kernel_launch(void* const* d_in, const int* in_sizes, int n_in,
                              void* d_out, int out_size, void* d_ws, size_t ws_size,
                              hipStream_t stream) {
    const float* c  = (const float*)d_in[0];
    const float* E  = (const float*)d_in[1];
    const float* Wq = (const float*)d_in[2];
    const float* bq = (const float*)d_in[3];
    const float* Wk = (const float*)d_in[4];
    // d_in[5] = bk: uniform logit shift, cancels in softmax
    const float* Wv = (const float*)d_in[6];
    const float* bv = (const float*)d_in[7];
    const float* Wo = (const float*)d_in[8];
    const float* bo = (const float*)d_in[9];
    // d_in[10] = top_k (always 5)
    float* ws  = (float*)d_ws;
    float* out = (float*)d_out;

    hipLaunchKernelGGL(k_front,  dim3(8),         dim3(256),  0, stream, c, Wq, bq, Wk, ws);
    hipLaunchKernelGGL(k_logits, dim3(K3_BLOCKS), dim3(256),  0, stream, E, ws);
    hipLaunchKernelGGL(k_mid,    dim3(1),         dim3(1024), 0, stream, E, ws);
    hipLaunchKernelGGL(k_h,      dim3(128),       dim3(64),   0, stream, Wv, bv, ws);
    hipLaunchKernelGGL(k_out,    dim3(512),       dim3(64),   0, stream, Wo, bo, ws, out);
}

// Round 12
// 110.128 us; speedup vs baseline: 1.2144x; 1.0157x over previous
//
#include <hip/hip_runtime.h>
#include <math.h>

#define D_IN 512
#define D_HID 128
#define D_OUT 512
#define N_ENT 262144

#define K3_BLOCKS 1024
#define WAVES_PER_BLOCK 8
#define ROWS_PER_BLOCK 256          // N_ENT / K3_BLOCKS
#define PAIRS_PER_WAVE 16           // 32 rows per wave, 2 per iteration

// ws float-offsets
#define KV_OFF   0                // 512 floats: kvec pre-scaled by 1/sqrt(H)
#define BM_OFF   512              // 1024 block maxes
#define BS_OFF   1536             // 1024 block sums
#define BT5_OFF_F 2560            // byte 10240 (8B aligned): 1024*5 u64 keys
#define U_OFF    12800            // 512 floats (16B aligned)
#define W_OFF    13312            // 1 float: sum of top5 normalized scores
#define H_OFF    13320            // 128 floats (8B aligned)

#define INV_SQRT_H 0.08838834764831845f  // 1/sqrt(128)

typedef float f32x4 __attribute__((ext_vector_type(4)));
typedef unsigned long long u64;

__device__ inline u64 pack_key(float v, int idx) {
    unsigned u = __float_as_uint(v);
    u = (u & 0x80000000u) ? ~u : (u | 0x80000000u);   // order-preserving
    return ((u64)u << 32) | (unsigned)(~idx);          // ties -> smaller idx wins
}
__device__ inline float unpack_val(u64 k) {
    unsigned o = (unsigned)(k >> 32);
    unsigned u = (o & 0x80000000u) ? (o & 0x7FFFFFFFu) : ~o;
    return __uint_as_float(u);
}
__device__ inline int unpack_idx(u64 k) { return (int)~(unsigned)(k & 0xFFFFFFFFu); }

#define INS5(kk) do { u64 _k = (kk); if (_k > t4) {            \
    if (_k > t0)      { t4=t3;t3=t2;t2=t1;t1=t0;t0=_k; }       \
    else if (_k > t1) { t4=t3;t3=t2;t2=t1;t1=_k; }             \
    else if (_k > t2) { t4=t3;t3=t2;t2=_k; }                   \
    else if (_k > t3) { t4=t3;t3=_k; }                         \
    else              { t4=_k; } } } while (0)

// ---------- K1: fused q = Wq@c+bq (redundant/block) + kvec chunk ----------
__global__ __launch_bounds__(256) void k_front(const float* __restrict__ c,
        const float* __restrict__ Wq, const float* __restrict__ bq,
        const float* __restrict__ Wk, float* __restrict__ ws) {
    __shared__ float qpart[256];
    __shared__ float qs[D_HID];
    __shared__ float kpart[4][64];
    const int t = threadIdx.x;
    {   // phase 1: q[128], 2 threads per h
        const int h = t >> 1, half = t & 1;
        const f32x4* wq = (const f32x4*)(Wq + (h << 9) + (half << 8));
        const f32x4* cv = (const f32x4*)(c + (half << 8));
        float acc = 0.f;
        #pragma unroll 8
        for (int j = 0; j < 64; ++j) {
            f32x4 a = wq[j], b = cv[j];
            acc += a.x*b.x + a.y*b.y + a.z*b.z + a.w*b.w;
        }
        qpart[t] = acc;
    }
    __syncthreads();
    if (t < D_HID) qs[t] = qpart[2*t] + qpart[2*t+1] + bq[t];
    __syncthreads();
    {   // phase 2: kvec[d0..d0+64), wave g covers h in [32g,32g+32)
        const int g = t >> 6, d = t & 63;
        const int d0 = blockIdx.x * 64;
        const float* col = Wk + (size_t)(g * 32) * D_IN + d0 + d;
        float acc = 0.f;
        #pragma unroll 8
        for (int h = 0; h < 32; ++h) acc += col[(size_t)h * D_IN] * qs[g*32 + h];
        kpart[g][d] = acc;
    }
    __syncthreads();
    if (t < 64) {
        float kv = kpart[0][t] + kpart[1][t] + kpart[2][t] + kpart[3][t];
        ws[KV_OFF + blockIdx.x*64 + t] = kv * INV_SQRT_H;   // pre-scale
    }
}

// ---------- K2: logits + online softmax + per-block top5 (packed u64) ----------
// R11's locality win amplified: 512-thread blocks (8 waves), 1024 blocks.
// Wave w takes row pairs base + 2w + 16k -> at any instant the block's 8
// waves read 16 contiguous rows (32 KB burst); 1024 sequential streams.
__global__ __launch_bounds__(512, 8) void k_logits(const float* __restrict__ E,
                                                   float* __restrict__ ws) {
    const int t = threadIdx.x;
    const int l = t & 63;
    const int w = t >> 6;
    const long base = (long)blockIdx.x * ROWS_PER_BLOCK;
    const long r0   = base + 2 * w;             // this wave's first row

    const f32x4* kv = (const f32x4*)(ws + KV_OFF);
    const f32x4 k0 = kv[l], k1 = kv[64 + l];

    float m = -INFINITY, s = 0.f;
    u64 t0 = 0, t1 = 0, t2 = 0, t3 = 0, t4 = 0;   // 0 < any real key

    const f32x4* rp = (const f32x4*)(E + r0 * (long)D_IN) + l;
    for (int k = 0; k < PAIRS_PER_WAVE; ++k, rp += 2048) {   // +16 rows/iter
        f32x4 a0 = __builtin_nontemporal_load(rp);
        f32x4 a1 = __builtin_nontemporal_load(rp + 64);
        f32x4 b0 = __builtin_nontemporal_load(rp + 128);
        f32x4 b1 = __builtin_nontemporal_load(rp + 192);
        float d0 = a0.x*k0.x + a0.y*k0.y + a0.z*k0.z + a0.w*k0.w
                 + a1.x*k1.x + a1.y*k1.y + a1.z*k1.z + a1.w*k1.w;
        float d1 = b0.x*k0.x + b0.y*k0.y + b0.z*k0.z + b0.w*k0.w
                 + b1.x*k1.x + b1.y*k1.y + b1.z*k1.z + b1.w*k1.w;
        #pragma unroll
        for (int mm = 32; mm > 0; mm >>= 1) {   // two independent chains, ILP
            d0 += __shfl_xor(d0, mm, 64);
            d1 += __shfl_xor(d1, mm, 64);
        }
        // kvec pre-scaled: d0/d1 ARE the logits
        float nm = fmaxf(m, fmaxf(d0, d1));
        s = s * __expf(m - nm) + __expf(d0 - nm) + __expf(d1 - nm);
        m = nm;
        const int idx = (int)r0 + 16 * k;
        INS5(pack_key(d0, idx));
        INS5(pack_key(d1, idx + 1));
    }

    __shared__ float sm[WAVES_PER_BLOCK], ss[WAVES_PER_BLOCK];
    __shared__ u64 skey[WAVES_PER_BLOCK][5];
    if (l == 0) {
        sm[w] = m; ss[w] = s;
        skey[w][0]=t0; skey[w][1]=t1; skey[w][2]=t2; skey[w][3]=t3; skey[w][4]=t4;
    }
    __syncthreads();
    if (t == 0) {
        float M = sm[0];
        #pragma unroll
        for (int j = 1; j < WAVES_PER_BLOCK; ++j) M = fmaxf(M, sm[j]);
        float S = 0.f;
        #pragma unroll
        for (int j = 0; j < WAVES_PER_BLOCK; ++j) S += ss[j] * __expf(sm[j] - M);
        u64 t0=0,t1=0,t2=0,t3=0,t4=0;
        #pragma unroll
        for (int j = 0; j < WAVES_PER_BLOCK*5; ++j) INS5(skey[j/5][j%5]);
        const int b = blockIdx.x;
        ws[BM_OFF + b] = M;
        ws[BS_OFF + b] = S;
        u64* bt = (u64*)ws + (BT5_OFF_F/2) + (size_t)b * 5;
        bt[0]=t0; bt[1]=t1; bt[2]=t2; bt[3]=t3; bt[4]=t4;
    }
}

// ---------- K3: global top5 -> M -> Z -> weights -> u  (1 block x 1024) ----------
__global__ __launch_bounds__(1024) void k_mid(const float* __restrict__ E,
                                              float* __restrict__ ws) {
    __shared__ u64   wc[16][5];
    __shared__ float selv[5];
    __shared__ int   seli[5];
    __shared__ float wn[5];
    __shared__ float zp[16];
    __shared__ float Zsh;
    const int t = threadIdx.x;
    const int l = t & 63;
    const int w = t >> 6;
    const u64* cand = (const u64*)ws + (BT5_OFF_F/2);

    // local top5 over 5 candidates each (1024*5 total)
    u64 t0=0,t1=0,t2=0,t3=0,t4=0;
    #pragma unroll
    for (int j = 0; j < 5; ++j) INS5(cand[t + j*1024]);

    // wave top5: 5 rounds of extract-max (keys unique -> exactly one advancer)
    {
        int pos = 0;
        u64 g0=0,g1=0,g2=0,g3=0,g4=0;
        #pragma unroll
        for (int r = 0; r < 5; ++r) {
            u64 head = pos==0?t0 : pos==1?t1 : pos==2?t2 : pos==3?t3 : pos==4?t4 : 0ULL;
            u64 wm = head;
            #pragma unroll
            for (int mm = 1; mm < 64; mm <<= 1) {
                u64 o = __shfl_xor(wm, mm, 64);
                wm = (o > wm) ? o : wm;
            }
            if (head == wm && wm != 0ULL) pos++;
            if (r==0) g0=wm; else if (r==1) g1=wm; else if (r==2) g2=wm;
            else if (r==3) g3=wm; else g4=wm;
        }
        if (l == 0) { wc[w][0]=g0; wc[w][1]=g1; wc[w][2]=g2; wc[w][3]=g3; wc[w][4]=g4; }
    }
    __syncthreads();

    // cross-wave merge (wave 0; lanes 0..15 present list heads)
    if (t < 64) {
        int pos = 0;
        #pragma unroll
        for (int r = 0; r < 5; ++r) {
            u64 head = (t < 16 && pos < 5) ? wc[t][pos] : 0ULL;
            u64 wm = head;
            #pragma unroll
            for (int mm = 1; mm < 64; mm <<= 1) {
                u64 o = __shfl_xor(wm, mm, 64);
                wm = (o > wm) ? o : wm;
            }
            if (head == wm && wm != 0ULL) pos++;
            if (t == 0) { selv[r] = unpack_val(wm); seli[r] = unpack_idx(wm); }
        }
    }
    __syncthreads();

    const float M = selv[0];   // global max logit == top-1 value

    // Z = sum over blocks of S_b * exp(M_b - M)   (one block per thread)
    {
        float z = ws[BS_OFF + t] * __expf(ws[BM_OFF + t] - M);
        #pragma unroll
        for (int mm = 1; mm < 64; mm <<= 1) z += __shfl_xor(z, mm, 64);
        if (l == 0) zp[w] = z;
    }
    __syncthreads();
    if (t == 0) {
        float Z = 0.f;
        #pragma unroll
        for (int j = 0; j < 16; ++j) Z += zp[j];
        Zsh = Z;
    }
    __syncthreads();
    if (t < 8) {
        float Z = Zsh;
        if (t < 5) wn[t] = __expf(selv[t] - M) / Z;
    }
    __syncthreads();
    if (t == 0) ws[W_OFF] = wn[0]+wn[1]+wn[2]+wn[3]+wn[4];

    // u[d] = sum_r wn[r] * E[idx_r][d]
    if (t < D_IN) {
        float acc = 0.f;
        #pragma unroll
        for (int r = 0; r < 5; ++r)
            acc += wn[r] * E[(long)seli[r] * D_IN + t];
        ws[U_OFF + t] = acc;
    }
}

// ---------- K4: h = Wv @ u + W*bv  (128 blocks x 64) ----------
__global__ void k_h(const float* __restrict__ Wv, const float* __restrict__ bv,
                    float* __restrict__ ws) {
    const int j = blockIdx.x;
    const int l = threadIdx.x;
    const f32x4* row = (const f32x4*)(Wv + (size_t)j * D_IN);
    const f32x4* u   = (const f32x4*)(ws + U_OFF);
    f32x4 a0 = row[l], a1 = row[64 + l];
    f32x4 u0 = u[l],   u1 = u[64 + l];
    float d = a0.x*u0.x + a0.y*u0.y + a0.z*u0.z + a0.w*u0.w
            + a1.x*u1.x + a1.y*u1.y + a1.z*u1.z + a1.w*u1.w;
    #pragma unroll
    for (int m = 32; m > 0; m >>= 1) d += __shfl_xor(d, m, 64);
    if (l == 0) ws[H_OFF + j] = d + ws[W_OFF] * bv[j];
}

// ---------- K5: out = Wo @ h + bo  (512 blocks x 64) ----------
__global__ void k_out(const float* __restrict__ Wo, const float* __restrict__ bo,
                      const float* __restrict__ ws, float* __restrict__ out) {
    const int o = blockIdx.x;
    const int l = threadIdx.x;
    const float2* row = (const float2*)(Wo + (size_t)o * D_HID);
    const float2* h   = (const float2*)(ws + H_OFF);
    float2 a = row[l], hh = h[l];
    float d = a.x*hh.x + a.y*hh.y;
    #pragma unroll
    for (int m = 32; m > 0; m >>= 1) d += __shfl_xor(d, m, 64);
    if (l == 0) out[o] = d + bo[o];
}

extern "C" void kernel_launch(void* const* d_in, const int* in_sizes, int n_in,
                              void* d_out, int out_size, void* d_ws, size_t ws_size,
                              hipStream_t stream) {
    const float* c  = (const float*)d_in[0];
    const float* E  = (const float*)d_in[1];
    const float* Wq = (const float*)d_in[2];
    const float* bq = (const float*)d_in[3];
    const float* Wk = (const float*)d_in[4];
    // d_in[5] = bk: uniform logit shift, cancels in softmax
    const float* Wv = (const float*)d_in[6];
    const float* bv = (const float*)d_in[7];
    const float* Wo = (const float*)d_in[8];
    const float* bo = (const float*)d_in[9];
    // d_in[10] = top_k (always 5)
    float* ws  = (float*)d_ws;
    float* out = (float*)d_out;

    hipLaunchKernelGGL(k_front,  dim3(8),         dim3(256),  0, stream, c, Wq, bq, Wk, ws);
    hipLaunchKernelGGL(k_logits, dim3(K3_BLOCKS), dim3(512),  0, stream, E, ws);
    hipLaunchKernelGGL(k_mid,    dim3(1),         dim3(1024), 0, stream, E, ws);
    hipLaunchKernelGGL(k_h,      dim3(128),       dim3(64),   0, stream, Wv, bv, ws);
    hipLaunchKernelGGL(k_out,    dim3(512),       dim3(64),   0, stream, Wo, bo, ws, out);
}